// Round 8
// baseline (230.222 us; speedup 1.0000x reference)
//
#include <hip/hip_runtime.h>

typedef __bf16 bf16x8 __attribute__((ext_vector_type(8)));
typedef float  f32x4  __attribute__((ext_vector_type(4)));

#define N_SITES 400000
#define KVOL    27
#define NPAD    (N_SITES + 16)
#define ZROW    N_SITES                  // all-zero row for invalid neighbors

#define FB_BYTES  ((size_t)NPAD * 128)
#define WSB_BYTES ((size_t)KVOL * 8 * 64 * 16)
#define WS_NEED   (FB_BYTES + WSB_BYTES)

// ---------- weight repack: fp32 [27][64][64] -> bf16 MFMA B-fragments ----------
// Fragment (ko, ks, cb), position (lane, e) holds kernel[ko][ci][co],
// ci = ks*32 + (lane>>4)*8 + e, co = cb*16 + (lane&15).
__global__ __launch_bounds__(256) void conv_prep(const float* __restrict__ kern,
                                                 bf16x8* __restrict__ wsb) {
    int tid = blockIdx.x * 256 + threadIdx.x;
    if (tid >= KVOL * 2 * 4 * 64) return;
    int lane = tid & 63;
    int cb   = (tid >> 6) & 3;
    int ks   = (tid >> 8) & 1;
    int ko   = tid >> 9;
    int i = lane & 15, g = lane >> 4;
    int co = cb * 16 + i;
    bf16x8 v;
#pragma unroll
    for (int e = 0; e < 8; ++e) {
        int ci = ks * 32 + g * 8 + e;
        v[e] = (__bf16)kern[(ko * 64 + ci) * 64 + co];
    }
    wsb[tid] = v;
}

// ---------- feats fp32 -> bf16 (plus zero pad rows) ----------
__global__ __launch_bounds__(256) void prep_feats(const float* __restrict__ f,
                                                  bf16x8* __restrict__ dst) {
    int tid = blockIdx.x * 256 + threadIdx.x;
    if (tid >= NPAD * 64 / 8) return;
    bf16x8 v;
    if (tid < N_SITES * 64 / 8) {
        const f32x4* s = (const f32x4*)(f + (size_t)tid * 8);
        f32x4 a = s[0], b = s[1];
#pragma unroll
        for (int e = 0; e < 4; ++e) { v[e] = (__bf16)a[e]; v[e + 4] = (__bf16)b[e]; }
    } else {
#pragma unroll
        for (int e = 0; e < 8; ++e) v[e] = (__bf16)0.0f;
    }
    dst[tid] = v;
}

// ---------- gather 32 feats rows into wave-private LDS, 8 rows/instr ----------
// Instr j: lane l = 8p+c reads global row idx(8j+p), chunk (c ^ p) (source-side
// XOR swizzle); LDS dest linear lane*16 -> LDS[8j+p][slot c] = chunk c ^ p.
// Read side applies the same XOR -> conflict-free (verified: 0 in round 7).
__device__ __forceinline__ void gather32(const char* __restrict__ fbase, int Iv,
                                         int permbase, int coff, char* abuf) {
#pragma unroll
    for (int j = 0; j < 4; ++j) {
        int idx = __builtin_amdgcn_ds_bpermute(permbase + j * 32, Iv);
        unsigned r = ((unsigned)idx < (unsigned)N_SITES) ? (unsigned)idx
                                                         : (unsigned)ZROW;
        __builtin_amdgcn_global_load_lds(
            (const __attribute__((address_space(1))) char*)
                (fbase + (((size_t)r) << 7) + coff),
            (__attribute__((address_space(3))) char*)(abuf + j * 1024), 16, 0, 0);
    }
}

// ---------- 4 ds_read_b128 (XOR-swizzled) + 16 MFMA; B from registers ----------
__device__ __forceinline__ void mfma16_rb(const char* abuf, const bf16x8 Bf[8],
                                          int lane, f32x4 acc[2][4]) {
    const int i = lane & 15, g = lane >> 4;
    const int sw = i & 7;
    const int c0 = (g ^ sw) << 4;            // chunk g   (k = 8g..8g+7)
    const int c1 = ((4 + g) ^ sw) << 4;      // chunk 4+g (k = 32+8g..)
    bf16x8 A0[2], A1[2];
#pragma unroll
    for (int t = 0; t < 2; ++t) {
        const char* rowp = abuf + (t * 16 + i) * 128;
        A0[t] = *(const bf16x8*)(rowp + c0);
        A1[t] = *(const bf16x8*)(rowp + c1);
    }
#pragma unroll
    for (int cb = 0; cb < 4; ++cb)
#pragma unroll
        for (int t = 0; t < 2; ++t) {
            acc[t][cb] = __builtin_amdgcn_mfma_f32_16x16x32_bf16(A0[t], Bf[cb],     acc[t][cb], 0, 0, 0);
            acc[t][cb] = __builtin_amdgcn_mfma_f32_16x16x32_bf16(A1[t], Bf[4 + cb], acc[t][cb], 0, 0, 0);
        }
}

// ---------- main: barrier-FREE, wave-private A in LDS, B in registers ----------
// Per-iter vmem windows (pinned by sched_barrier):
//   [B(k) x8] [Iv(k+2) x1] [gather A(k+1) x4]  then vmcnt(13) retires gather(k).
__global__ __launch_bounds__(256, 4) void conv_main8(
    const char* __restrict__ fbase,      // bf16 feats, 128 B/row, +ZROW
    const int*  __restrict__ nmap,
    const float* __restrict__ bias,
    const bf16x8* __restrict__ wsb,
    float* __restrict__ out)
{
    __shared__ __align__(1024) char ldsa[4][2][4096];   // wave-private A dbuf

    const int lane = threadIdx.x & 63;
    const int wave = threadIdx.x >> 6;
    const int i = lane & 15, g = lane >> 4;
    const int row0 = blockIdx.x * 128 + wave * 32;      // exact: 3125*128 = 400000
    const int* nrow = nmap + row0 + (lane & 31);
    const int permbase = (lane >> 3) << 2;              // bpermute byte base
    const int coff = ((lane & 7) ^ (lane >> 3)) << 4;   // source-side XOR swizzle
    char* abase = ldsa[wave][0];
    const bf16x8* bbase = wsb + lane;

    float bv[4];
#pragma unroll
    for (int cb = 0; cb < 4; ++cb) bv[cb] = bias[cb * 16 + i];

    f32x4 acc[2][4] = {};
    int IvR[2];

    // ---- prologue: idx(0), idx(1) (pinned OLDER than gather(0)), A(0) ----
    {
        int Iv0 = nrow[0];
        IvR[1] = __builtin_nontemporal_load(nrow + (size_t)N_SITES);   // idx(1)
        __builtin_amdgcn_sched_barrier(0);
        gather32(fbase, Iv0, permbase, coff, abase);                   // A(0) -> buf0
        __builtin_amdgcn_sched_barrier(0);
    }

#pragma unroll
    for (int k = 0; k < KVOL; ++k) {
        // window 1: B(k) -> registers (8 vmem, coalesced, L2-hot)
        bf16x8 Bf[8];
#pragma unroll
        for (int f = 0; f < 8; ++f) Bf[f] = bbase[(k * 8 + f) * 64];
        __builtin_amdgcn_sched_barrier(0);
        // window 2: idx(k+2) (1 vmem)
        if (k + 2 < KVOL)
            IvR[(k + 2) & 1] = __builtin_nontemporal_load(nrow + (size_t)(k + 2) * N_SITES);
        __builtin_amdgcn_sched_barrier(0);
        // window 3: gather A(k+1) -> other LDS buf (4 vmem)
        if (k + 1 < KVOL)
            gather32(fbase, IvR[(k + 1) & 1], permbase, coff,
                     abase + ((k + 1) & 1) * 4096);
        __builtin_amdgcn_sched_barrier(0);
        // retire gather(k); keep B(k)+Iv+gather(k+1) in flight
        if (k < 25)       asm volatile("s_waitcnt vmcnt(13)" ::: "memory");
        else if (k == 25) asm volatile("s_waitcnt vmcnt(12)" ::: "memory");
        else              asm volatile("s_waitcnt vmcnt(8)"  ::: "memory");
        __builtin_amdgcn_sched_barrier(0);
        __builtin_amdgcn_s_setprio(1);
        mfma16_rb(abase + (k & 1) * 4096, Bf, lane, acc);
        __builtin_amdgcn_s_setprio(0);
        __builtin_amdgcn_sched_barrier(0);
    }

    // ---- epilogue: C/D layout col = lane&15, row = (lane>>4)*4 + reg ----
#pragma unroll
    for (int t = 0; t < 2; ++t)
#pragma unroll
        for (int cb = 0; cb < 4; ++cb)
#pragma unroll
            for (int r = 0; r < 4; ++r)
                __builtin_nontemporal_store(acc[t][cb][r] + bv[cb],
                    &out[(size_t)(row0 + t * 16 + g * 4 + r) * 64 + cb * 16 + i]);
}

// ---------- fallback (only if ws too small): round-1 kernel ----------
__global__ __launch_bounds__(256) void conv_main1(
    const float* __restrict__ feats,
    const int*   __restrict__ nmap,
    const float* __restrict__ bias,
    const bf16x8* __restrict__ wsb,
    float* __restrict__ out)
{
    const int lane = threadIdx.x & 63;
    const int wave = threadIdx.x >> 6;
    const int i = lane & 15;
    const int g = lane >> 4;
    const int row0 = (blockIdx.x * 4 + wave) * 32;

    f32x4 acc[2][4] = {};
    for (int k = 0; k < KVOL; ++k) {
        bf16x8 bfr[2][4];
#pragma unroll
        for (int ks = 0; ks < 2; ++ks)
#pragma unroll
            for (int cb = 0; cb < 4; ++cb)
                bfr[ks][cb] = wsb[(k * 8 + ks * 4 + cb) * 64 + lane];
#pragma unroll
        for (int t = 0; t < 2; ++t) {
            const int row = row0 + t * 16 + i;
            const int idx = nmap[k * N_SITES + row];
            const int src = idx < 0 ? 0 : idx;
            const f32x4* fp = (const f32x4*)(feats + (size_t)src * 64 + g * 8);
            f32x4 v0 = fp[0], v1 = fp[1], v2 = fp[8], v3 = fp[9];
            union { bf16x8 v; unsigned u[4]; } A0, A1;
#pragma unroll
            for (int e = 0; e < 4; ++e) {
                A0.v[e] = (__bf16)v0[e]; A0.v[e + 4] = (__bf16)v1[e];
                A1.v[e] = (__bf16)v2[e]; A1.v[e + 4] = (__bf16)v3[e];
            }
#pragma unroll
            for (int e = 0; e < 4; ++e) {
                A0.u[e] = (idx < 0) ? 0u : A0.u[e];
                A1.u[e] = (idx < 0) ? 0u : A1.u[e];
            }
#pragma unroll
            for (int cb = 0; cb < 4; ++cb)
                acc[t][cb] = __builtin_amdgcn_mfma_f32_16x16x32_bf16(A0.v, bfr[0][cb], acc[t][cb], 0, 0, 0);
#pragma unroll
            for (int cb = 0; cb < 4; ++cb)
                acc[t][cb] = __builtin_amdgcn_mfma_f32_16x16x32_bf16(A1.v, bfr[1][cb], acc[t][cb], 0, 0, 0);
        }
    }
    float bv[4];
#pragma unroll
    for (int cb = 0; cb < 4; ++cb) bv[cb] = bias[cb * 16 + i];
#pragma unroll
    for (int t = 0; t < 2; ++t)
#pragma unroll
        for (int cb = 0; cb < 4; ++cb)
#pragma unroll
            for (int r = 0; r < 4; ++r)
                out[(size_t)(row0 + t * 16 + g * 4 + r) * 64 + cb * 16 + i] =
                    acc[t][cb][r] + bv[cb];
}

extern "C" void kernel_launch(void* const* d_in, const int* in_sizes, int n_in,
                              void* d_out, int out_size, void* d_ws, size_t ws_size,
                              hipStream_t stream) {
    const float* feats = (const float*)d_in[0];
    const float* kern  = (const float*)d_in[1];
    const float* bias  = (const float*)d_in[2];
    const int*   nmap  = (const int*)d_in[3];
    float* out = (float*)d_out;

    if (ws_size >= WS_NEED) {
        bf16x8* fb  = (bf16x8*)d_ws;
        bf16x8* wsb = (bf16x8*)((char*)d_ws + FB_BYTES);
        prep_feats<<<(NPAD * 64 / 8 + 255) / 256, 256, 0, stream>>>(feats, fb);
        conv_prep<<<(KVOL * 2 * 4 * 64 + 255) / 256, 256, 0, stream>>>(kern, wsb);
        // 32 rows/wave, 4 waves/block -> 128 rows/block; 400000/128 = 3125 exactly
        conv_main8<<<3125, 256, 0, stream>>>((const char*)fb, nmap, bias, wsb, out);
    } else {
        bf16x8* wsb = (bf16x8*)d_ws;
        conv_prep<<<(KVOL * 2 * 4 * 64 + 255) / 256, 256, 0, stream>>>(kern, wsb);
        conv_main1<<<3125, 256, 0, stream>>>(feats, nmap, bias, wsb, out);
    }
}

// Round 9
// 184.418 us; speedup vs baseline: 1.2484x; 1.2484x over previous
//
#include <hip/hip_runtime.h>

typedef __bf16 bf16x8 __attribute__((ext_vector_type(8)));
typedef float  f32x4  __attribute__((ext_vector_type(4)));

#define N_SITES 400000
#define KVOL    27
#define NPAD    (N_SITES + 16)
#define ZROW    N_SITES                  // all-zero row for invalid neighbors

#define FB_BYTES  ((size_t)NPAD * 128)
#define WSB_BYTES ((size_t)KVOL * 8 * 64 * 16)
#define WS_NEED   (FB_BYTES + WSB_BYTES)

// ---------- weight repack: fp32 [27][64][64] -> bf16 MFMA B-fragments ----------
// Fragment (ko, ks, cb), position (lane, e) holds kernel[ko][ci][co],
// ci = ks*32 + (lane>>4)*8 + e, co = cb*16 + (lane&15).
__global__ __launch_bounds__(256) void conv_prep(const float* __restrict__ kern,
                                                 bf16x8* __restrict__ wsb) {
    int tid = blockIdx.x * 256 + threadIdx.x;
    if (tid >= KVOL * 2 * 4 * 64) return;
    int lane = tid & 63;
    int cb   = (tid >> 6) & 3;
    int ks   = (tid >> 8) & 1;
    int ko   = tid >> 9;
    int i = lane & 15, g = lane >> 4;
    int co = cb * 16 + i;
    bf16x8 v;
#pragma unroll
    for (int e = 0; e < 8; ++e) {
        int ci = ks * 32 + g * 8 + e;
        v[e] = (__bf16)kern[(ko * 64 + ci) * 64 + co];
    }
    wsb[tid] = v;
}

// ---------- feats fp32 -> bf16 (plus zero pad rows) ----------
__global__ __launch_bounds__(256) void prep_feats(const float* __restrict__ f,
                                                  bf16x8* __restrict__ dst) {
    int tid = blockIdx.x * 256 + threadIdx.x;
    if (tid >= NPAD * 64 / 8) return;
    bf16x8 v;
    if (tid < N_SITES * 64 / 8) {
        const f32x4* s = (const f32x4*)(f + (size_t)tid * 8);
        f32x4 a = s[0], b = s[1];
#pragma unroll
        for (int e = 0; e < 4; ++e) { v[e] = (__bf16)a[e]; v[e + 4] = (__bf16)b[e]; }
    } else {
#pragma unroll
        for (int e = 0; e < 8; ++e) v[e] = (__bf16)0.0f;
    }
    dst[tid] = v;
}

// ---------- stage one offset's B fragments (8 KB) with 512 threads: 1 instr ----------
__device__ __forceinline__ void stage_b9(const bf16x8* __restrict__ wsb, int k,
                                         char* buf) {
    const char* g = (const char*)(wsb + (size_t)k * 8 * 64);
    int wave = threadIdx.x >> 6;
    __builtin_amdgcn_global_load_lds(
        (const __attribute__((address_space(1))) char*)(g + (size_t)threadIdx.x * 16),
        (__attribute__((address_space(3))) char*)(buf + wave * 1024), 16, 0, 0);
}

// ---------- gather 32 feats rows into wave-private LDS, 8 rows/instr ----------
// Lane l = 8p+c reads global row idx(8j+p), chunk (c ^ p) (source-side XOR
// swizzle); linear LDS dest -> LDS[8j+p][slot c] = chunk c^p. Read applies the
// same XOR -> conflict-free (0 conflicts measured, rounds 7/8).
__device__ __forceinline__ void gather32(const char* __restrict__ fbase, int Iv,
                                         int permbase, int coff, char* abuf) {
#pragma unroll
    for (int j = 0; j < 4; ++j) {
        int idx = __builtin_amdgcn_ds_bpermute(permbase + j * 32, Iv);
        unsigned r = ((unsigned)idx < (unsigned)N_SITES) ? (unsigned)idx
                                                         : (unsigned)ZROW;
        __builtin_amdgcn_global_load_lds(
            (const __attribute__((address_space(1))) char*)
                (fbase + (((size_t)r) << 7) + coff),
            (__attribute__((address_space(3))) char*)(abuf + j * 1024), 16, 0, 0);
    }
}

// ---------- 12 ds_read_b128 + 16 MFMA: A (swizzled) and B from LDS ----------
__device__ __forceinline__ void mfma16_ab(const char* abuf, const char* bbuf,
                                          int lane, f32x4 acc[2][4]) {
    const int i = lane & 15, g = lane >> 4;
    const int sw = i & 7;
    const int c0 = (g ^ sw) << 4;            // chunk g   (k = 8g..8g+7)
    const int c1 = ((4 + g) ^ sw) << 4;      // chunk 4+g (k = 32+8g..)
    bf16x8 A0[2], A1[2], B0[4], B1[4];
#pragma unroll
    for (int t = 0; t < 2; ++t) {
        const char* rowp = abuf + (t * 16 + i) * 128;
        A0[t] = *(const bf16x8*)(rowp + c0);
        A1[t] = *(const bf16x8*)(rowp + c1);
    }
    const bf16x8* B = (const bf16x8*)bbuf;
#pragma unroll
    for (int cb = 0; cb < 4; ++cb) {
        B0[cb] = B[cb * 64 + lane];
        B1[cb] = B[(4 + cb) * 64 + lane];
    }
#pragma unroll
    for (int cb = 0; cb < 4; ++cb)
#pragma unroll
        for (int t = 0; t < 2; ++t) {
            acc[t][cb] = __builtin_amdgcn_mfma_f32_16x16x32_bf16(A0[t], B0[cb], acc[t][cb], 0, 0, 0);
            acc[t][cb] = __builtin_amdgcn_mfma_f32_16x16x32_bf16(A1[t], B1[cb], acc[t][cb], 0, 0, 0);
        }
}

// ---------- main: 8 waves/block, 32 rows/wave, 80 KB LDS, 2 blocks/CU ----------
// Steady iter k:
//   [idx(k+2) x1]                       (FIRST vmem -> bpermute wait next iter
//                                        retires only this, never gathers)
//   [gather A(k+1) x4]                  (wave-private LDS, distance-1)
//   vmcnt(5)                            (retires g(k)+st(k); keeps i(k+2)+g(k+1))
//   s_barrier                           (all waves' st(k) done -> B(k) ready)
//   [stage B(k+1) x1]                   (post-barrier: dbuf race-free)
//   MFMA(k)                             (12 ds_read_b128 + 16 MFMA)
__global__ __launch_bounds__(512, 4) void conv_main9(
    const char* __restrict__ fbase,      // bf16 feats, 128 B/row, +ZROW
    const int*  __restrict__ nmap,
    const float* __restrict__ bias,
    const bf16x8* __restrict__ wsb,
    float* __restrict__ out)
{
    __shared__ __align__(1024) char ldsb[2][8192];      // B double-buffer (block)
    __shared__ __align__(1024) char ldsa[8][2][4096];   // A dbuf, wave-private

    const int lane = threadIdx.x & 63;
    const int wave = threadIdx.x >> 6;
    const int i = lane & 15, g = lane >> 4;
    const int row0 = blockIdx.x * 256 + wave * 32;
    int rowme = row0 + (lane & 31);
    if (rowme > N_SITES - 1) rowme = N_SITES - 1;       // tail clamp (in-bounds)
    const int* nrow = nmap + rowme;
    const int permbase = (lane >> 3) << 2;              // bpermute byte base
    const int coff = ((lane & 7) ^ (lane >> 3)) << 4;   // source-side XOR swizzle
    char* abase = ldsa[wave][0];

    float bv[4];
#pragma unroll
    for (int cb = 0; cb < 4; ++cb) bv[cb] = bias[cb * 16 + i];

    f32x4 acc[2][4] = {};
    int IvR[2];

    // ---- prologue: i(0); [i(1); g(0)x4; st(0)] -> outstanding = 6 ----
    {
        int Iv0 = nrow[0];                               // compiler waits before bpermute
        __builtin_amdgcn_sched_barrier(0);
        IvR[1] = __builtin_nontemporal_load(nrow + (size_t)N_SITES);   // i(1) FIRST
        __builtin_amdgcn_sched_barrier(0);
        gather32(fbase, Iv0, permbase, coff, abase);     // g(0) x4
        __builtin_amdgcn_sched_barrier(0);
        stage_b9(wsb, 0, ldsb[0]);                       // st(0) x1
        __builtin_amdgcn_sched_barrier(0);
    }

#pragma unroll
    for (int k = 0; k < KVOL; ++k) {
        // window 1: idx(k+2) — first, so next iter's bpermute wait is harmless
        if (k + 2 < KVOL)
            IvR[(k + 2) & 1] = __builtin_nontemporal_load(nrow + (size_t)(k + 2) * N_SITES);
        __builtin_amdgcn_sched_barrier(0);
        // window 2: gather A(k+1) (bpermute auto-retires i(k+1) only)
        if (k + 1 < KVOL)
            gather32(fbase, IvR[(k + 1) & 1], permbase, coff,
                     abase + ((k + 1) & 1) * 4096);
        __builtin_amdgcn_sched_barrier(0);
        // retire g(k) + st(k); keep i(k+2) + g(k+1) in flight
        if (k < 25)       asm volatile("s_waitcnt vmcnt(5)" ::: "memory");
        else if (k == 25) asm volatile("s_waitcnt vmcnt(4)" ::: "memory");
        else              asm volatile("s_waitcnt vmcnt(0)" ::: "memory");
        __builtin_amdgcn_sched_barrier(0);
        __builtin_amdgcn_s_barrier();                    // B(k) ready block-wide
        __builtin_amdgcn_sched_barrier(0);
        if (k + 1 < KVOL)
            stage_b9(wsb, k + 1, ldsb[(k + 1) & 1]);     // post-barrier: race-free
        __builtin_amdgcn_sched_barrier(0);
        __builtin_amdgcn_s_setprio(1);
        mfma16_ab(abase + (k & 1) * 4096, ldsb[k & 1], lane, acc);
        __builtin_amdgcn_s_setprio(0);
        __builtin_amdgcn_sched_barrier(0);
    }

    // ---- epilogue: C/D layout col = lane&15, row = (lane>>4)*4 + reg ----
    if (row0 < N_SITES) {                                // whole-wave tail guard
#pragma unroll
        for (int t = 0; t < 2; ++t)
#pragma unroll
            for (int cb = 0; cb < 4; ++cb)
#pragma unroll
                for (int r = 0; r < 4; ++r)
                    __builtin_nontemporal_store(acc[t][cb][r] + bv[cb],
                        &out[(size_t)(row0 + t * 16 + g * 4 + r) * 64 + cb * 16 + i]);
    }
}

// ---------- fallback (only if ws too small): round-1 kernel ----------
__global__ __launch_bounds__(256) void conv_main1(
    const float* __restrict__ feats,
    const int*   __restrict__ nmap,
    const float* __restrict__ bias,
    const bf16x8* __restrict__ wsb,
    float* __restrict__ out)
{
    const int lane = threadIdx.x & 63;
    const int wave = threadIdx.x >> 6;
    const int i = lane & 15;
    const int g = lane >> 4;
    const int row0 = (blockIdx.x * 4 + wave) * 32;

    f32x4 acc[2][4] = {};
    for (int k = 0; k < KVOL; ++k) {
        bf16x8 bfr[2][4];
#pragma unroll
        for (int ks = 0; ks < 2; ++ks)
#pragma unroll
            for (int cb = 0; cb < 4; ++cb)
                bfr[ks][cb] = wsb[(k * 8 + ks * 4 + cb) * 64 + lane];
#pragma unroll
        for (int t = 0; t < 2; ++t) {
            const int row = row0 + t * 16 + i;
            const int idx = nmap[k * N_SITES + row];
            const int src = idx < 0 ? 0 : idx;
            const f32x4* fp = (const f32x4*)(feats + (size_t)src * 64 + g * 8);
            f32x4 v0 = fp[0], v1 = fp[1], v2 = fp[8], v3 = fp[9];
            union { bf16x8 v; unsigned u[4]; } A0, A1;
#pragma unroll
            for (int e = 0; e < 4; ++e) {
                A0.v[e] = (__bf16)v0[e]; A0.v[e + 4] = (__bf16)v1[e];
                A1.v[e] = (__bf16)v2[e]; A1.v[e + 4] = (__bf16)v3[e];
            }
#pragma unroll
            for (int e = 0; e < 4; ++e) {
                A0.u[e] = (idx < 0) ? 0u : A0.u[e];
                A1.u[e] = (idx < 0) ? 0u : A1.u[e];
            }
#pragma unroll
            for (int cb = 0; cb < 4; ++cb)
                acc[t][cb] = __builtin_amdgcn_mfma_f32_16x16x32_bf16(A0.v, bfr[0][cb], acc[t][cb], 0, 0, 0);
#pragma unroll
            for (int cb = 0; cb < 4; ++cb)
                acc[t][cb] = __builtin_amdgcn_mfma_f32_16x16x32_bf16(A1.v, bfr[1][cb], acc[t][cb], 0, 0, 0);
        }
    }
    float bv[4];
#pragma unroll
    for (int cb = 0; cb < 4; ++cb) bv[cb] = bias[cb * 16 + i];
#pragma unroll
    for (int t = 0; t < 2; ++t)
#pragma unroll
        for (int cb = 0; cb < 4; ++cb)
#pragma unroll
            for (int r = 0; r < 4; ++r)
                out[(size_t)(row0 + t * 16 + g * 4 + r) * 64 + cb * 16 + i] =
                    acc[t][cb][r] + bv[cb];
}

extern "C" void kernel_launch(void* const* d_in, const int* in_sizes, int n_in,
                              void* d_out, int out_size, void* d_ws, size_t ws_size,
                              hipStream_t stream) {
    const float* feats = (const float*)d_in[0];
    const float* kern  = (const float*)d_in[1];
    const float* bias  = (const float*)d_in[2];
    const int*   nmap  = (const int*)d_in[3];
    float* out = (float*)d_out;

    if (ws_size >= WS_NEED) {
        bf16x8* fb  = (bf16x8*)d_ws;
        bf16x8* wsb = (bf16x8*)((char*)d_ws + FB_BYTES);
        prep_feats<<<(NPAD * 64 / 8 + 255) / 256, 256, 0, stream>>>(feats, fb);
        conv_prep<<<(KVOL * 2 * 4 * 64 + 255) / 256, 256, 0, stream>>>(kern, wsb);
        // 32 rows/wave, 8 waves/block -> 256 rows/block; ceil(400000/256) = 1563
        conv_main9<<<1563, 512, 0, stream>>>((const char*)fb, nmap, bias, wsb, out);
    } else {
        bf16x8* wsb = (bf16x8*)d_ws;
        conv_prep<<<(KVOL * 2 * 4 * 64 + 255) / 256, 256, 0, stream>>>(kern, wsb);
        conv_main1<<<3125, 256, 0, stream>>>(feats, nmap, bias, wsb, out);
    }
}

// Round 10
// 184.037 us; speedup vs baseline: 1.2510x; 1.0021x over previous
//
#include <hip/hip_runtime.h>

typedef __bf16 bf16x8 __attribute__((ext_vector_type(8)));
typedef float  f32x4  __attribute__((ext_vector_type(4)));

#define N_SITES 400000
#define KVOL    27
#define NPAD    (N_SITES + 16)
#define ZROW    N_SITES                  // all-zero row for invalid neighbors

#define FB_BYTES  ((size_t)NPAD * 128)
#define WSB_BYTES ((size_t)KVOL * 8 * 64 * 16)
#define WS_NEED   (FB_BYTES + WSB_BYTES)

// ---------- weight repack: fp32 [27][64][64] -> bf16 MFMA B-fragments ----------
// Fragment (ko, ks, cb), position (lane, e) holds kernel[ko][ci][co],
// ci = ks*32 + (lane>>4)*8 + e, co = cb*16 + (lane&15).
__global__ __launch_bounds__(256) void conv_prep(const float* __restrict__ kern,
                                                 bf16x8* __restrict__ wsb) {
    int tid = blockIdx.x * 256 + threadIdx.x;
    if (tid >= KVOL * 2 * 4 * 64) return;
    int lane = tid & 63;
    int cb   = (tid >> 6) & 3;
    int ks   = (tid >> 8) & 1;
    int ko   = tid >> 9;
    int i = lane & 15, g = lane >> 4;
    int co = cb * 16 + i;
    bf16x8 v;
#pragma unroll
    for (int e = 0; e < 8; ++e) {
        int ci = ks * 32 + g * 8 + e;
        v[e] = (__bf16)kern[(ko * 64 + ci) * 64 + co];
    }
    wsb[tid] = v;
}

// ---------- feats fp32 -> bf16 (plus zero pad rows) ----------
__global__ __launch_bounds__(256) void prep_feats(const float* __restrict__ f,
                                                  bf16x8* __restrict__ dst) {
    int tid = blockIdx.x * 256 + threadIdx.x;
    if (tid >= NPAD * 64 / 8) return;
    bf16x8 v;
    if (tid < N_SITES * 64 / 8) {
        const f32x4* s = (const f32x4*)(f + (size_t)tid * 8);
        f32x4 a = s[0], b = s[1];
#pragma unroll
        for (int e = 0; e < 4; ++e) { v[e] = (__bf16)a[e]; v[e + 4] = (__bf16)b[e]; }
    } else {
#pragma unroll
        for (int e = 0; e < 8; ++e) v[e] = (__bf16)0.0f;
    }
    dst[tid] = v;
}

// ---------- stage one offset's B fragments (8 KB) with 512 threads: 1 instr ----------
__device__ __forceinline__ void stage_b9(const bf16x8* __restrict__ wsb, int k,
                                         char* buf) {
    const char* g = (const char*)(wsb + (size_t)k * 8 * 64);
    int wave = threadIdx.x >> 6;
    __builtin_amdgcn_global_load_lds(
        (const __attribute__((address_space(1))) char*)(g + (size_t)threadIdx.x * 16),
        (__attribute__((address_space(3))) char*)(buf + wave * 1024), 16, 0, 0);
}

// ---------- gather 16 feats rows into wave-private LDS, 8 rows/instr ----------
// Lane l = 8p+c reads global row idx(8j+p), chunk (c ^ p) (source-side XOR
// swizzle); linear LDS dest -> LDS[8j+p][slot c] = chunk c^p. Read applies the
// same XOR -> conflict-free (0 conflicts measured, rounds 7-9).
__device__ __forceinline__ void gather16(const char* __restrict__ fbase, int Iv,
                                         int permbase, int coff, char* abuf) {
#pragma unroll
    for (int j = 0; j < 2; ++j) {
        int idx = __builtin_amdgcn_ds_bpermute(permbase + j * 32, Iv);
        unsigned r = ((unsigned)idx < (unsigned)N_SITES) ? (unsigned)idx
                                                         : (unsigned)ZROW;
        __builtin_amdgcn_global_load_lds(
            (const __attribute__((address_space(1))) char*)
                (fbase + (((size_t)r) << 7) + coff),
            (__attribute__((address_space(3))) char*)(abuf + j * 1024), 16, 0, 0);
    }
}

// ---------- 10 ds_read_b128 + 8 MFMA: A (swizzled) and B from LDS ----------
__device__ __forceinline__ void mfma8_ab(const char* abuf, const char* bbuf,
                                         int lane, f32x4 acc[4]) {
    const int i = lane & 15, g = lane >> 4;
    const int sw = i & 7;
    const int c0 = (g ^ sw) << 4;            // chunk g   (k = 8g..8g+7)
    const int c1 = ((4 + g) ^ sw) << 4;      // chunk 4+g (k = 32+8g..)
    const char* rowp = abuf + i * 128;
    bf16x8 A0 = *(const bf16x8*)(rowp + c0);
    bf16x8 A1 = *(const bf16x8*)(rowp + c1);
    const bf16x8* B = (const bf16x8*)bbuf;
#pragma unroll
    for (int cb = 0; cb < 4; ++cb) {
        bf16x8 b0 = B[cb * 64 + lane];
        bf16x8 b1 = B[(4 + cb) * 64 + lane];
        acc[cb] = __builtin_amdgcn_mfma_f32_16x16x32_bf16(A0, b0, acc[cb], 0, 0, 0);
        acc[cb] = __builtin_amdgcn_mfma_f32_16x16x32_bf16(A1, b1, acc[cb], 0, 0, 0);
    }
}

// ---------- main: 8 waves/block, 16 rows/wave, 48 KB LDS, 3 blocks/CU ----------
// Steady iter k (ledger hand-traced, queue oldest->newest):
//   [idx(k+2) x1]   (FIRST vmem: next iter's bpermute wait retires only this)
//   [gather A(k+1) x2]
//   vmcnt(3)        (retires g(k)x2 + st(k); keeps i(k+2) + g(k+1) in flight)
//   s_barrier       (B(k) staged block-wide)
//   [stage B(k+1) x1]
//   MFMA(k)         (2 A + 8 B ds_read_b128, 8 MFMA)
__global__ __launch_bounds__(512, 6) void conv_main10(
    const char* __restrict__ fbase,      // bf16 feats, 128 B/row, +ZROW
    const int*  __restrict__ nmap,
    const float* __restrict__ bias,
    const bf16x8* __restrict__ wsb,
    float* __restrict__ out)
{
    __shared__ __align__(1024) char ldsb[2][8192];      // B double-buffer (block)
    __shared__ __align__(1024) char ldsa[8][2][2048];   // A dbuf, wave-private

    const int lane = threadIdx.x & 63;
    const int wave = threadIdx.x >> 6;
    const int i = lane & 15, g = lane >> 4;
    const int row0 = blockIdx.x * 128 + wave * 16;      // exact: 3125*128 = 400000
    const int* nrow = nmap + row0 + i;                  // 16 idx, 4x replicated
    const int permbase = (lane >> 3) << 2;              // bpermute byte base
    const int coff = ((lane & 7) ^ (lane >> 3)) << 4;   // source-side XOR swizzle
    char* abase = ldsa[wave][0];

    float bv[4];
#pragma unroll
    for (int cb = 0; cb < 4; ++cb) bv[cb] = bias[cb * 16 + i];

    f32x4 acc[4] = {};
    int IvR[2];

    // ---- prologue: i(0); [i(1); g(0)x2; st(0)] -> outstanding = 4 ----
    {
        int Iv0 = nrow[0];                               // compiler waits before bpermute
        __builtin_amdgcn_sched_barrier(0);
        IvR[1] = __builtin_nontemporal_load(nrow + (size_t)N_SITES);   // i(1) FIRST
        __builtin_amdgcn_sched_barrier(0);
        gather16(fbase, Iv0, permbase, coff, abase);     // g(0) x2
        __builtin_amdgcn_sched_barrier(0);
        stage_b9(wsb, 0, ldsb[0]);                       // st(0) x1
        __builtin_amdgcn_sched_barrier(0);
    }

#pragma unroll
    for (int k = 0; k < KVOL; ++k) {
        // window 1: idx(k+2) — first, so next iter's bpermute wait is harmless
        if (k + 2 < KVOL)
            IvR[(k + 2) & 1] = __builtin_nontemporal_load(nrow + (size_t)(k + 2) * N_SITES);
        __builtin_amdgcn_sched_barrier(0);
        // window 2: gather A(k+1) (bpermute auto-retires i(k+1) only)
        if (k + 1 < KVOL)
            gather16(fbase, IvR[(k + 1) & 1], permbase, coff,
                     abase + ((k + 1) & 1) * 2048);
        __builtin_amdgcn_sched_barrier(0);
        // retire g(k) + st(k); keep i(k+2) + g(k+1) in flight
        if (k < 25)       asm volatile("s_waitcnt vmcnt(3)" ::: "memory");
        else if (k == 25) asm volatile("s_waitcnt vmcnt(2)" ::: "memory");
        else              asm volatile("s_waitcnt vmcnt(0)" ::: "memory");
        __builtin_amdgcn_sched_barrier(0);
        __builtin_amdgcn_s_barrier();                    // B(k) ready block-wide
        __builtin_amdgcn_sched_barrier(0);
        if (k + 1 < KVOL)
            stage_b9(wsb, k + 1, ldsb[(k + 1) & 1]);     // post-barrier: race-free
        __builtin_amdgcn_sched_barrier(0);
        __builtin_amdgcn_s_setprio(1);
        mfma8_ab(abase + (k & 1) * 2048, ldsb[k & 1], lane, acc);
        __builtin_amdgcn_s_setprio(0);
        __builtin_amdgcn_sched_barrier(0);
    }

    // ---- epilogue: C/D layout col = lane&15, row = (lane>>4)*4 + reg ----
#pragma unroll
    for (int cb = 0; cb < 4; ++cb)
#pragma unroll
        for (int r = 0; r < 4; ++r)
            __builtin_nontemporal_store(acc[cb][r] + bv[cb],
                &out[(size_t)(row0 + g * 4 + r) * 64 + cb * 16 + i]);
}

// ---------- fallback (only if ws too small): round-1 kernel ----------
__global__ __launch_bounds__(256) void conv_main1(
    const float* __restrict__ feats,
    const int*   __restrict__ nmap,
    const float* __restrict__ bias,
    const bf16x8* __restrict__ wsb,
    float* __restrict__ out)
{
    const int lane = threadIdx.x & 63;
    const int wave = threadIdx.x >> 6;
    const int i = lane & 15;
    const int g = lane >> 4;
    const int row0 = (blockIdx.x * 4 + wave) * 32;

    f32x4 acc[2][4] = {};
    for (int k = 0; k < KVOL; ++k) {
        bf16x8 bfr[2][4];
#pragma unroll
        for (int ks = 0; ks < 2; ++ks)
#pragma unroll
            for (int cb = 0; cb < 4; ++cb)
                bfr[ks][cb] = wsb[(k * 8 + ks * 4 + cb) * 64 + lane];
#pragma unroll
        for (int t = 0; t < 2; ++t) {
            const int row = row0 + t * 16 + i;
            const int idx = nmap[k * N_SITES + row];
            const int src = idx < 0 ? 0 : idx;
            const f32x4* fp = (const f32x4*)(feats + (size_t)src * 64 + g * 8);
            f32x4 v0 = fp[0], v1 = fp[1], v2 = fp[8], v3 = fp[9];
            union { bf16x8 v; unsigned u[4]; } A0, A1;
#pragma unroll
            for (int e = 0; e < 4; ++e) {
                A0.v[e] = (__bf16)v0[e]; A0.v[e + 4] = (__bf16)v1[e];
                A1.v[e] = (__bf16)v2[e]; A1.v[e + 4] = (__bf16)v3[e];
            }
#pragma unroll
            for (int e = 0; e < 4; ++e) {
                A0.u[e] = (idx < 0) ? 0u : A0.u[e];
                A1.u[e] = (idx < 0) ? 0u : A1.u[e];
            }
#pragma unroll
            for (int cb = 0; cb < 4; ++cb)
                acc[t][cb] = __builtin_amdgcn_mfma_f32_16x16x32_bf16(A0.v, bfr[0][cb], acc[t][cb], 0, 0, 0);
#pragma unroll
            for (int cb = 0; cb < 4; ++cb)
                acc[t][cb] = __builtin_amdgcn_mfma_f32_16x16x32_bf16(A1.v, bfr[1][cb], acc[t][cb], 0, 0, 0);
        }
    }
    float bv[4];
#pragma unroll
    for (int cb = 0; cb < 4; ++cb) bv[cb] = bias[cb * 16 + i];
#pragma unroll
    for (int t = 0; t < 2; ++t)
#pragma unroll
        for (int cb = 0; cb < 4; ++cb)
#pragma unroll
            for (int r = 0; r < 4; ++r)
                out[(size_t)(row0 + t * 16 + g * 4 + r) * 64 + cb * 16 + i] =
                    acc[t][cb][r] + bv[cb];
}

extern "C" void kernel_launch(void* const* d_in, const int* in_sizes, int n_in,
                              void* d_out, int out_size, void* d_ws, size_t ws_size,
                              hipStream_t stream) {
    const float* feats = (const float*)d_in[0];
    const float* kern  = (const float*)d_in[1];
    const float* bias  = (const float*)d_in[2];
    const int*   nmap  = (const int*)d_in[3];
    float* out = (float*)d_out;

    if (ws_size >= WS_NEED) {
        bf16x8* fb  = (bf16x8*)d_ws;
        bf16x8* wsb = (bf16x8*)((char*)d_ws + FB_BYTES);
        prep_feats<<<(NPAD * 64 / 8 + 255) / 256, 256, 0, stream>>>(feats, fb);
        conv_prep<<<(KVOL * 2 * 4 * 64 + 255) / 256, 256, 0, stream>>>(kern, wsb);
        // 16 rows/wave, 8 waves/block -> 128 rows/block; 400000/128 = 3125 exactly
        conv_main10<<<3125, 512, 0, stream>>>((const char*)fb, nmap, bias, wsb, out);
    } else {
        bf16x8* wsb = (bf16x8*)d_ws;
        conv_prep<<<(KVOL * 2 * 4 * 64 + 255) / 256, 256, 0, stream>>>(kern, wsb);
        conv_main1<<<3125, 256, 0, stream>>>(feats, nmap, bias, wsb, out);
    }
}